// Round 18
// baseline (476.007 us; speedup 1.0000x reference)
//
#include <hip/hip_runtime.h>
#include <math.h>

#define NN 51200
#define EE 1638400
#define GG 512
#define INF 16
#define HCC 128
#define NB 400        // buckets: dst >> 7, 128 nodes each
#define TILE 4096     // edges per hist tile
#define TILEB 2048    // edges per bin tile (800 tiles)
#define CSRCAP 4608   // LDS staging capacity in k_csr
#define NBLK (NN / 4) // node-blocks per head-pair phase in k_attn

typedef float vf2 __attribute__((ext_vector_type(2)));
typedef short v8s __attribute__((ext_vector_type(8)));
typedef float v4f __attribute__((ext_vector_type(4)));
#define FMA2 __builtin_elementwise_fma
#define MIN2 __builtin_elementwise_min
#define MAX2 __builtin_elementwise_max

// xl/xr are HEAD-MAJOR: plane h = xl + h*NN*32, row = 128 B (one head's 32 ch).
// k_attn sweeps HEAD PAIRS in grid phases (pair = blockIdx.x/NBLK).
// binned aliases h: bin/csr complete before attn1 writes h.
// lin2 = split-bf16 MFMA GEMM (A_hi*B_hi + A_hi*B_lo + A_lo*B_hi, fp32 acc).

__device__ __forceinline__ int wave_incl_scan(int v, int lane) {
#pragma unroll
    for (int d = 1; d < 64; d <<= 1) {
        int y = __shfl_up(v, d);
        if (lane >= d) v += y;
    }
    return v;
}

__device__ __forceinline__ unsigned short bf16_rtne(float f) {
    unsigned u = __builtin_bit_cast(unsigned, f);
    unsigned r = u + 0x7FFFu + ((u >> 16) & 1u);
    return (unsigned short)(r >> 16);
}

// FUSED: blocks [0,NB)        = histogram tile (512 thr, 8 loads each)
//        blocks [NB,NB+NN/4)  = layer-1 linear (4 rows each, head-major)
//        blocks [+8]          = split-bf16 prep of l2 weights (frag order)
__global__ __launch_bounds__(512) void k_histlin1(const int* __restrict__ ei,
                                                  int* __restrict__ bcnt,
                                                  const float* __restrict__ x,
                                                  const float* __restrict__ Wl,
                                                  const float* __restrict__ bl,
                                                  const float* __restrict__ Wr,
                                                  const float* __restrict__ br,
                                                  float* __restrict__ xl,
                                                  float* __restrict__ xr,
                                                  const float* __restrict__ W2l,
                                                  const float* __restrict__ W2r,
                                                  unsigned short* __restrict__ Bhi,
                                                  unsigned short* __restrict__ Blo) {
    __shared__ int h[NB];
    __shared__ float sx[4][INF];
    int t = threadIdx.x;
    if (blockIdx.x < NB) {
        // ---- histogram over one 4096-edge tile ----
        if (t < NB) h[t] = 0;
        __syncthreads();
        int e0 = blockIdx.x * TILE;
#pragma unroll
        for (int s = 0; s < 8; s++) {
            int d = ei[EE + e0 + s * 512 + t];
            atomicAdd(&h[d >> 7], 1);
        }
        __syncthreads();
        if (t < NB && h[t]) atomicAdd(&bcnt[t], h[t]);
    } else if (blockIdx.x < NB + NN / 4) {
        // ---- layer-1 linear: 4 rows per block ----
        int bid = blockIdx.x - NB;
        int j = t & 127;
        int ty = t >> 7;
        int row = bid * 4 + ty;
        if (t < 64) {
            sx[t >> 4][t & 15] = x[(size_t)(bid * 4 + (t >> 4)) * INF + (t & 15)];
        }
        __syncthreads();
        float al = bl[j], ar = br[j];
#pragma unroll
        for (int k = 0; k < INF; k++) {
            float xv = sx[ty][k];
            al = fmaf(xv, Wl[k * HCC + j], al);
            ar = fmaf(xv, Wr[k * HCC + j], ar);
        }
        size_t s = ((size_t)(j >> 5) * NN + row) * 32 + (j & 31);
        xl[s] = al;
        xr[s] = ar;
    } else {
        // ---- bf16 split-prep of l2 weights into fragment order ----
        int gt = (blockIdx.x - NB - NN / 4) * 512 + t;   // 0..4095
        int ks = gt >> 10;
        int rem = gt & 1023;
        int nt = rem >> 6;
        int lane = rem & 63;
        int n = nt * 16 + (lane & 15);
        int kbase = ks * 32 + (lane >> 4) * 8;
        const float* src = (n < 128) ? (W2l + n) : (W2r + n - 128);
        unsigned short hi8[8], lo8[8];
#pragma unroll
        for (int j = 0; j < 8; j++) {
            float v = src[(size_t)(kbase + j) * HCC];
            unsigned short hb = bf16_rtne(v);
            float hf = __builtin_bit_cast(float, (unsigned)hb << 16);
            hi8[j] = hb;
            lo8[j] = bf16_rtne(v - hf);
        }
        size_t idx = (size_t)gt * 8;
#pragma unroll
        for (int j = 0; j < 8; j++) { Bhi[idx + j] = hi8[j]; Blo[idx + j] = lo8[j]; }
    }
}

__global__ __launch_bounds__(512) void k_scan2(const int* __restrict__ bcnt,
                                               int* __restrict__ bbase,
                                               int* __restrict__ gcur,
                                               int* __restrict__ rowptr) {
    __shared__ int sc[512];
    int t = threadIdx.x;
    int v = (t < NB) ? bcnt[t] : 0;
    sc[t] = v;
    __syncthreads();
    for (int off = 1; off < 512; off <<= 1) {
        int u = (t >= off) ? sc[t - off] : 0;
        __syncthreads();
        sc[t] += u;
        __syncthreads();
    }
    if (t < NB) { int ex = sc[t] - v; bbase[t] = ex; gcur[t] = ex; }
    if (t == 0) { bbase[NB] = EE; rowptr[NN] = EE; }
}

// tile-local rank by bucket in LDS; packed (dst<<16 | src) uint32 entries.
// 800 tiles x 2048 edges (NB=400 buckets unchanged).
__global__ __launch_bounds__(512) void k_bin(const int* __restrict__ ei,
                                             int* __restrict__ gcur,
                                             unsigned* __restrict__ binned) {
    __shared__ int hh[NB], lexcl[NB], lcur[NB], baseg[NB];
    __shared__ unsigned stage[TILEB];
    __shared__ int wsum[8];
    int t = threadIdx.x;
    int lane = t & 63, w = t >> 6;
    if (t < NB) hh[t] = 0;
    __syncthreads();
    int e0 = blockIdx.x * TILEB;
    int sv[4], dv[4];
#pragma unroll
    for (int s = 0; s < 4; s++) {
        int e = e0 + s * 512 + t;
        sv[s] = ei[e];
        dv[s] = ei[EE + e];
        atomicAdd(&hh[dv[s] >> 7], 1);
    }
    __syncthreads();
    int c0 = 0, c1 = 0;
    if (t < NB / 2) { c0 = hh[2 * t]; c1 = hh[2 * t + 1]; }
    int tot = c0 + c1;
    int incl = wave_incl_scan(tot, lane);
    if (lane == 63) wsum[w] = incl;
    __syncthreads();
    int woff = 0;
    for (int i = 0; i < w; i++) woff += wsum[i];
    int ex = incl + woff - tot;
    if (t < NB / 2) {
        lexcl[2 * t] = ex;          lcur[2 * t] = ex;
        lexcl[2 * t + 1] = ex + c0; lcur[2 * t + 1] = ex + c0;
        baseg[2 * t] = atomicAdd(&gcur[2 * t], c0);
        baseg[2 * t + 1] = atomicAdd(&gcur[2 * t + 1], c1);
    }
    __syncthreads();
#pragma unroll
    for (int s = 0; s < 4; s++) {
        int b = dv[s] >> 7;
        int r = atomicAdd(&lcur[b], 1);
        stage[r] = (unsigned)sv[s] | ((unsigned)dv[s] << 16);
    }
    __syncthreads();
#pragma unroll
    for (int s = 0; s < 4; s++) {
        int idx = s * 512 + t;
        unsigned p = stage[idx];
        int b = (int)(p >> 23);
        binned[baseg[b] + idx - lexcl[b]] = p;
    }
}

// per-bucket: per-(node,phase) histogram + scan -> rowptr & phase-grouped col.
// 512 threads; binned staged in LDS during pass 1 (overflow -> global).
__global__ __launch_bounds__(512) void k_csr(const unsigned* __restrict__ binned,
                                             const int* __restrict__ bbase,
                                             int* __restrict__ rowptr,
                                             int* __restrict__ col) {
    int b = blockIdx.x;
    int base = bbase[b];
    int cnt = bbase[b + 1] - base;
    __shared__ int nh[1024], ncur[1024];   // [node_local(128)][phase(8)]
    __shared__ unsigned sbin[CSRCAP];
    __shared__ int wsum[8];
    int t = threadIdx.x;
    int lane = t & 63, w = t >> 6;
    nh[t] = 0;
    nh[t + 512] = 0;
    __syncthreads();
    for (int e = t; e < cnt; e += 512) {
        unsigned p = binned[base + e];
        if (e < CSRCAP) sbin[e] = p;
        unsigned src = p & 0xFFFFu;
        int key = (int)(((p >> 16) & 127u) << 3) | (int)(src >> 13);
        atomicAdd(&nh[key], 1);
    }
    __syncthreads();
    int c0 = nh[2 * t], c1 = nh[2 * t + 1];
    int tot = c0 + c1;
    int incl = wave_incl_scan(tot, lane);
    if (lane == 63) wsum[w] = incl;
    __syncthreads();
    int woff = 0;
    for (int i = 0; i < w; i++) woff += wsum[i];
    int tex = incl + woff - tot;
    ncur[2 * t] = base + tex;
    ncur[2 * t + 1] = base + tex + c0;
    if ((t & 3) == 0) rowptr[(b << 7) + (t >> 2)] = base + tex;
    __syncthreads();
    for (int e = t; e < cnt; e += 512) {
        unsigned p = (e < CSRCAP) ? sbin[e] : binned[base + e];
        unsigned src = p & 0xFFFFu;
        int key = (int)(((p >> 16) & 127u) << 3) | (int)(src >> 13);
        int r = atomicAdd(&ncur[key], 1);
        col[r] = (int)src;
    }
}

// ---------------- layer-2 linear: split-bf16 MFMA GEMM ----------------
__global__ __launch_bounds__(256) void k_lin2(const float* __restrict__ hin,
                                              const unsigned short* __restrict__ Bhi,
                                              const unsigned short* __restrict__ Blo,
                                              const float* __restrict__ bl,
                                              const float* __restrict__ br,
                                              float* __restrict__ outl,
                                              float* __restrict__ outr) {
    const int tid = threadIdx.x;
    const int wv = tid >> 6;
    const int lane = tid & 63;
    const int m = lane & 15;
    const int quad = lane >> 4;
    const int r0 = blockIdx.x * 64 + wv * 16;
    const float* arow = hin + (size_t)(r0 + m) * HCC + quad * 8;
    const v8s* bh = (const v8s*)Bhi;
    const v8s* bo = (const v8s*)Blo;

    v4f acc[16];
#pragma unroll
    for (int nt = 0; nt < 16; nt++) acc[nt] = (v4f){0.f, 0.f, 0.f, 0.f};

#pragma unroll
    for (int ks = 0; ks < 4; ks++) {
        const float4 av0 = *(const float4*)(arow + ks * 32);
        const float4 av1 = *(const float4*)(arow + ks * 32 + 4);
        const float af[8] = {av0.x, av0.y, av0.z, av0.w, av1.x, av1.y, av1.z, av1.w};
        v8s ahi, alo;
#pragma unroll
        for (int e = 0; e < 8; e++) {
            unsigned short hb = bf16_rtne(af[e]);
            float hf = __builtin_bit_cast(float, (unsigned)hb << 16);
            ahi[e] = (short)hb;
            alo[e] = (short)bf16_rtne(af[e] - hf);
        }
        const int base = ks * 16 * 64 + lane;
#pragma unroll
        for (int nt = 0; nt < 16; nt++) {
            v8s bhv = bh[base + nt * 64];
            v8s blv = bo[base + nt * 64];
            acc[nt] = __builtin_amdgcn_mfma_f32_16x16x32_bf16(ahi, bhv, acc[nt], 0, 0, 0);
            acc[nt] = __builtin_amdgcn_mfma_f32_16x16x32_bf16(ahi, blv, acc[nt], 0, 0, 0);
            acc[nt] = __builtin_amdgcn_mfma_f32_16x16x32_bf16(alo, bhv, acc[nt], 0, 0, 0);
        }
    }
#pragma unroll
    for (int nt = 0; nt < 16; nt++) {
        int n = nt * 16 + m;
        int c = n & 127;
        float bv = (n < 128) ? bl[c] : br[c];
        float* outp = ((n < 128) ? outl : outr) + (size_t)(c >> 5) * NN * 32 + (c & 31);
#pragma unroll
        for (int r = 0; r < 4; r++) {
            int row = r0 + quad * 4 + r;
            outp[(size_t)row * 32] = acc[nt][r] + bv;
        }
    }
}

// ---------------- GATv2 attention, one wave per (node, head-PAIR) ---------
__global__ __launch_bounds__(256) void k_attn(const int* __restrict__ rowptr,
                                              const int* __restrict__ col,
                                              const float* __restrict__ xl,
                                              const float* __restrict__ xr,
                                              const float* __restrict__ att,
                                              const float* __restrict__ bias,
                                              float* __restrict__ hout) {
    const int wave = threadIdx.x >> 6;
    const int lane = threadIdx.x & 63;
    const int sub = lane >> 3;
    const int hl = (lane >> 2) & 1;
    const int hq = lane & 3;
    const int pair = blockIdx.x / NBLK;
    const int n = (blockIdx.x - pair * NBLK) * 4 + wave;
    const int head = 2 * pair + hl;

    const float* xlh = xl + (size_t)head * NN * 32;
    const float* xrp = xr + ((size_t)head * NN + n) * 32 + hq * 8;
    const float4 xrv0 = *(const float4*)(xrp);
    const float4 xrv1 = *(const float4*)(xrp + 4);
    const float4 at0 = *(const float4*)(att + head * 32 + hq * 8);
    const float4 at1 = *(const float4*)(att + head * 32 + hq * 8 + 4);
    const vf2 xr01 = {xrv0.x, xrv0.y}, xr23 = {xrv0.z, xrv0.w};
    const vf2 xr45 = {xrv1.x, xrv1.y}, xr67 = {xrv1.z, xrv1.w};
    const vf2 at01 = {at0.x, at0.y}, at23 = {at0.z, at0.w};
    const vf2 at45 = {at1.x, at1.y}, at67 = {at1.z, at1.w};
    const vf2 Z2 = {0.f, 0.f}, C2 = {0.2f, 0.2f};
    const unsigned choff = (unsigned)hq * 32u;

    const int base = rowptr[n];
    const int deg = rowptr[n + 1] - base;

    float m = -INFINITY, l = 0.f;
    vf2 a01 = Z2, a23 = Z2, a45 = Z2, a67 = Z2;

    for (int i0 = 0; i0 < deg; i0 += 64) {
        int mye = 0;
        if (i0 + lane < deg) mye = col[base + i0 + lane];
        const int cnt = min(64, deg - i0);
        const int events = (cnt + 15) >> 4;
        for (int g = 0; g < events; ++g) {
            float4 v0[2], v1[2];
            float p[2];
#pragma unroll
            for (int k = 0; k < 2; ++k) {
                const int src = __shfl(mye, 16 * g + 8 * k + sub);
                const unsigned voff = ((unsigned)src << 7) + choff;
                v0[k] = *(const float4*)((const char*)xlh + voff);
                v1[k] = *(const float4*)((const char*)xlh + voff + 16);
            }
#pragma unroll
            for (int k = 0; k < 2; ++k) {
                const vf2 v01 = {v0[k].x, v0[k].y}, v23 = {v0[k].z, v0[k].w};
                const vf2 v45 = {v1[k].x, v1[k].y}, v67 = {v1[k].z, v1[k].w};
                vf2 e, kk, p2;
                e = v01 + xr01; kk = FMA2(C2, MIN2(e, Z2), MAX2(e, Z2)); p2 = kk * at01;
                e = v23 + xr23; kk = FMA2(C2, MIN2(e, Z2), MAX2(e, Z2)); p2 = FMA2(kk, at23, p2);
                e = v45 + xr45; kk = FMA2(C2, MIN2(e, Z2), MAX2(e, Z2)); p2 = FMA2(kk, at45, p2);
                e = v67 + xr67; kk = FMA2(C2, MIN2(e, Z2), MAX2(e, Z2)); p2 = FMA2(kk, at67, p2);
                float pp = p2.x + p2.y;
                pp += __shfl_xor(pp, 1);
                pp += __shfl_xor(pp, 2);
                if ((16 * g + 8 * k + sub) >= cnt) pp = -INFINITY;
                p[k] = pp;
            }
            float pm = fmaxf(p[0], p[1]);
            pm = fmaxf(pm, __shfl_xor(pm, 8));
            pm = fmaxf(pm, __shfl_xor(pm, 16));
            pm = fmaxf(pm, __shfl_xor(pm, 32));
            const float mn = fmaxf(m, pm);
            const float sc = __expf(m - mn);
            const float w0 = __expf(p[0] - mn);
            const float w1 = __expf(p[1] - mn);
            l = fmaf(l, sc, w0 + w1);
            const vf2 S = {sc, sc}, W0 = {w0, w0}, W1 = {w1, w1};
            const vf2 u01 = {v0[0].x, v0[0].y}, u23 = {v0[0].z, v0[0].w};
            const vf2 u45 = {v1[0].x, v1[0].y}, u67 = {v1[0].z, v1[0].w};
            const vf2 t01 = {v0[1].x, v0[1].y}, t23 = {v0[1].z, v0[1].w};
            const vf2 t45 = {v1[1].x, v1[1].y}, t67 = {v1[1].z, v1[1].w};
            a01 = FMA2(W1, t01, FMA2(W0, u01, a01 * S));
            a23 = FMA2(W1, t23, FMA2(W0, u23, a23 * S));
            a45 = FMA2(W1, t45, FMA2(W0, u45, a45 * S));
            a67 = FMA2(W1, t67, FMA2(W0, u67, a67 * S));
            m = mn;
        }
    }
    l += __shfl_xor(l, 8);
    l += __shfl_xor(l, 16);
    l += __shfl_xor(l, 32);
    float af[8] = {a01.x, a01.y, a23.x, a23.y, a45.x, a45.y, a67.x, a67.y};
#pragma unroll
    for (int i = 0; i < 8; i++) {
        af[i] += __shfl_xor(af[i], 8);
        af[i] += __shfl_xor(af[i], 16);
        af[i] += __shfl_xor(af[i], 32);
    }
    const float inv = 1.f / (l + 1e-16f);
    if (sub == 0) {
        const float4 b0 = *(const float4*)(bias + head * 32 + hq * 8);
        const float4 b1 = *(const float4*)(bias + head * 32 + hq * 8 + 4);
        float4 o0, o1;
        o0.x = fmaxf(fmaf(af[0], inv, b0.x), 0.f);
        o0.y = fmaxf(fmaf(af[1], inv, b0.y), 0.f);
        o0.z = fmaxf(fmaf(af[2], inv, b0.z), 0.f);
        o0.w = fmaxf(fmaf(af[3], inv, b0.w), 0.f);
        o1.x = fmaxf(fmaf(af[4], inv, b1.x), 0.f);
        o1.y = fmaxf(fmaf(af[5], inv, b1.y), 0.f);
        o1.z = fmaxf(fmaf(af[6], inv, b1.z), 0.f);
        o1.w = fmaxf(fmaf(af[7], inv, b1.w), 0.f);
        float* hp = hout + (size_t)n * HCC + head * 32 + hq * 8;
        *(float4*)(hp) = o0;
        *(float4*)(hp + 4) = o1;
    }
}

// ---------------- pool (sorted batch) + MLP head ----------------
__global__ __launch_bounds__(128) void k_head(const float* __restrict__ h,
                                              const int* __restrict__ batch,
                                              const float* __restrict__ fc1W, const float* __restrict__ fc1b,
                                              const float* __restrict__ bn1g, const float* __restrict__ bn1b,
                                              const float* __restrict__ fc2W, const float* __restrict__ fc2b,
                                              const float* __restrict__ bn2g, const float* __restrict__ bn2b,
                                              const float* __restrict__ fc3W, const float* __restrict__ fc3b,
                                              float* __restrict__ out) {
    int g = blockIdx.x;
    int j = threadIdx.x;
    __shared__ float buf[HCC], buf2[HCC];
    int lo = 0, hi = NN;
    while (lo < hi) { int mid = (lo + hi) >> 1; if (batch[mid] < g) lo = mid + 1; else hi = mid; }
    int s = lo;
    lo = 0; hi = NN;
    while (lo < hi) { int mid = (lo + hi) >> 1; if (batch[mid] < g + 1) lo = mid + 1; else hi = mid; }
    int e = lo;
    float s0 = 0.f, s1 = 0.f, s2 = 0.f, s3 = 0.f;
    int n = s;
    for (; n + 3 < e; n += 4) {
        s0 += h[(size_t)n * HCC + j];
        s1 += h[(size_t)(n + 1) * HCC + j];
        s2 += h[(size_t)(n + 2) * HCC + j];
        s3 += h[(size_t)(n + 3) * HCC + j];
    }
    for (; n < e; n++) s0 += h[(size_t)n * HCC + j];
    float sum = (s0 + s1) + (s2 + s3);
    float cnt = (float)(e - s);
    buf[j] = sum / fmaxf(cnt, 1.0f);
    __syncthreads();
    const float SQ = 1.00000499998749994f;
    float a = fc1b[j];
    for (int k = 0; k < HCC; k++) a = fmaf(buf[k], fc1W[k * HCC + j], a);
    a = fmaf(a, bn1g[j] / SQ, bn1b[j]);
    a = fmaxf(a, 0.f);
    buf2[j] = a;
    __syncthreads();
    a = fc2b[j];
    for (int k = 0; k < HCC; k++) a = fmaf(buf2[k], fc2W[k * HCC + j], a);
    a = fmaf(a, bn2g[j] / SQ, bn2b[j]);
    a = fmaxf(a, 0.f);
    buf[j] = a;
    __syncthreads();
    if (j < 2) {
        float o = fc3b[j];
        for (int k = 0; k < HCC; k++) o = fmaf(buf[k], fc3W[k * 2 + j], o);
        out[g * 2 + j] = o;
    }
}

extern "C" void kernel_launch(void* const* d_in, const int* in_sizes, int n_in,
                              void* d_out, int out_size, void* d_ws, size_t ws_size,
                              hipStream_t stream) {
    const float* x      = (const float*)d_in[0];
    const int*   ei     = (const int*)d_in[1];
    const int*   batch  = (const int*)d_in[2];
    const float* l1_Wl  = (const float*)d_in[3];
    const float* l1_bl  = (const float*)d_in[4];
    const float* l1_Wr  = (const float*)d_in[5];
    const float* l1_br  = (const float*)d_in[6];
    const float* l1_att = (const float*)d_in[7];
    const float* l1_bias= (const float*)d_in[8];
    const float* l2_Wl  = (const float*)d_in[9];
    const float* l2_bl  = (const float*)d_in[10];
    const float* l2_Wr  = (const float*)d_in[11];
    const float* l2_br  = (const float*)d_in[12];
    const float* l2_att = (const float*)d_in[13];
    const float* l2_bias= (const float*)d_in[14];
    const float* fc1_W  = (const float*)d_in[15];
    const float* fc1_b  = (const float*)d_in[16];
    const float* bn1_g  = (const float*)d_in[17];
    const float* bn1_b  = (const float*)d_in[18];
    const float* fc2_W  = (const float*)d_in[19];
    const float* fc2_b  = (const float*)d_in[20];
    const float* bn2_g  = (const float*)d_in[21];
    const float* bn2_b  = (const float*)d_in[22];
    const float* fc3_W  = (const float*)d_in[23];
    const float* fc3_b  = (const float*)d_in[24];
    float* out = (float*)d_out;

    float* xl = (float*)d_ws;
    float* xr = xl + (size_t)NN * HCC;
    float* h  = xr + (size_t)NN * HCC;
    int* rowptr = (int*)(h + (size_t)NN * HCC);
    int* col    = rowptr + (NN + 1);
    int* bcnt   = col + EE;
    int* bbase  = bcnt + NB;
    int* gcur   = bbase + (NB + 1);
    uintptr_t bp = ((uintptr_t)(gcur + NB) + 15) & ~(uintptr_t)15;
    unsigned short* Bhi = (unsigned short*)bp;       // 64 KB, frag-ordered
    unsigned short* Blo = Bhi + 32768;               // 64 KB
    // binned (6.5 MB) aliases h (26 MB): bin/csr complete before attn1 writes h
    unsigned* binned = (unsigned*)h;

    // CSR build (+ fused layer-1 linear + l2-weight bf16 split-prep)
    hipMemsetAsync(bcnt, 0, NB * sizeof(int), stream);
    k_histlin1<<<NB + NN / 4 + 8, 512, 0, stream>>>(ei, bcnt,
                                                    x, l1_Wl, l1_bl, l1_Wr, l1_br, xl, xr,
                                                    l2_Wl, l2_Wr, Bhi, Blo);
    k_scan2<<<1, 512, 0, stream>>>(bcnt, bbase, gcur, rowptr);
    k_bin<<<EE / TILEB, 512, 0, stream>>>(ei, gcur, binned);
    k_csr<<<NB, 512, 0, stream>>>(binned, bbase, rowptr, col);

    // layer 1 attention
    k_attn<<<2 * NBLK, 256, 0, stream>>>(rowptr, col, xl, xr, l1_att, l1_bias, h);

    // layer 2
    k_lin2<<<NN / 64, 256, 0, stream>>>(h, Bhi, Blo, l2_bl, l2_br, xl, xr);
    k_attn<<<2 * NBLK, 256, 0, stream>>>(rowptr, col, xl, xr, l2_att, l2_bias, h);

    // pool + MLP head
    k_head<<<GG, 128, 0, stream>>>(h, batch, fc1_W, fc1_b, bn1_g, bn1_b,
                                   fc2_W, fc2_b, bn2_g, bn2_b, fc3_W, fc3_b, out);
}

// Round 19
// 441.894 us; speedup vs baseline: 1.0772x; 1.0772x over previous
//
#include <hip/hip_runtime.h>
#include <math.h>

#define NN 51200
#define EE 1638400
#define GG 512
#define INF 16
#define HCC 128
#define NB 400        // buckets: dst >> 7, 128 nodes each
#define TILE 4096     // edges per k_bin block
#define CSRCAP 4608   // LDS staging capacity in k_csr (bucket avg 4096, max ~4400)
#define NBLK (NN / 4) // node-blocks per head-pair phase in k_attn

typedef float vf2 __attribute__((ext_vector_type(2)));
typedef short v8s __attribute__((ext_vector_type(8)));
typedef float v4f __attribute__((ext_vector_type(4)));
#define FMA2 __builtin_elementwise_fma
#define MIN2 __builtin_elementwise_min
#define MAX2 __builtin_elementwise_max

// xl/xr are HEAD-MAJOR: plane h = xl + h*NN*32, row = 128 B (one head's 32 ch).
// k_attn sweeps HEAD PAIRS in grid phases (pair = blockIdx.x/NBLK).
// binned aliases h: lin1 (fused with bin) writes xl/xr concurrently.
// lin2 = split-bf16 MFMA GEMM (A_hi*B_hi + A_hi*B_lo + A_lo*B_hi, fp32 acc).

__device__ __forceinline__ int wave_incl_scan(int v, int lane) {
#pragma unroll
    for (int d = 1; d < 64; d <<= 1) {
        int y = __shfl_up(v, d);
        if (lane >= d) v += y;
    }
    return v;
}

__device__ __forceinline__ unsigned short bf16_rtne(float f) {
    unsigned u = __builtin_bit_cast(unsigned, f);
    unsigned r = u + 0x7FFFu + ((u >> 16) & 1u);
    return (unsigned short)(r >> 16);
}

// ---------------- CSR build (binned two-level counting sort) ----------------
__global__ __launch_bounds__(512) void k_hist(const int* __restrict__ ei,
                                              int* __restrict__ bcnt) {
    __shared__ int h[NB];
    int t = threadIdx.x;
    if (t < NB) h[t] = 0;
    __syncthreads();
    int e0 = blockIdx.x * TILE;
#pragma unroll
    for (int s = 0; s < 8; s++) {
        int d = ei[EE + e0 + s * 512 + t];
        atomicAdd(&h[d >> 7], 1);
    }
    __syncthreads();
    if (t < NB && h[t]) atomicAdd(&bcnt[t], h[t]);
}

__global__ __launch_bounds__(512) void k_scan2(const int* __restrict__ bcnt,
                                               int* __restrict__ bbase,
                                               int* __restrict__ gcur,
                                               int* __restrict__ rowptr) {
    __shared__ int sc[512];
    int t = threadIdx.x;
    int v = (t < NB) ? bcnt[t] : 0;
    sc[t] = v;
    __syncthreads();
    for (int off = 1; off < 512; off <<= 1) {
        int u = (t >= off) ? sc[t - off] : 0;
        __syncthreads();
        sc[t] += u;
        __syncthreads();
    }
    if (t < NB) { int ex = sc[t] - v; bbase[t] = ex; gcur[t] = ex; }
    if (t == 0) { bbase[NB] = EE; rowptr[NN] = EE; }
}

// FUSED: blocks [0,NB)            = tile-local bucket rank -> binned
//        blocks [NB, NB+NN/4)     = layer-1 linear (4 rows each, head-major)
//        blocks [NB+NN/4, +8)     = split-bf16 prep of l2 weights (frag order)
__global__ __launch_bounds__(512) void k_binlin1(const int* __restrict__ ei,
                                                 int* __restrict__ gcur,
                                                 unsigned* __restrict__ binned,
                                                 const float* __restrict__ x,
                                                 const float* __restrict__ Wl,
                                                 const float* __restrict__ bl,
                                                 const float* __restrict__ Wr,
                                                 const float* __restrict__ br,
                                                 float* __restrict__ xl,
                                                 float* __restrict__ xr,
                                                 const float* __restrict__ W2l,
                                                 const float* __restrict__ W2r,
                                                 unsigned short* __restrict__ Bhi,
                                                 unsigned short* __restrict__ Blo) {
    __shared__ int h[512];
    __shared__ int lexcl[NB], lcur[NB], baseg[NB];
    __shared__ unsigned stage[TILE];
    __shared__ int wsum[8];
    __shared__ float sx[4][INF];
    int t = threadIdx.x;
    if (blockIdx.x < NB) {
        // ---- bin pass ----
        int lane = t & 63, w = t >> 6;
        h[t] = 0;
        __syncthreads();
        int e0 = blockIdx.x * TILE;
        int sv[8], dv[8];
#pragma unroll
        for (int s = 0; s < 8; s++) {
            int e = e0 + s * 512 + t;
            sv[s] = ei[e];
            dv[s] = ei[EE + e];
            atomicAdd(&h[dv[s] >> 7], 1);
        }
        __syncthreads();
        int myh = h[t];
        int incl = wave_incl_scan(myh, lane);
        if (lane == 63) wsum[w] = incl;
        __syncthreads();
        int woff = 0;
        for (int i = 0; i < w; i++) woff += wsum[i];
        incl += woff;
        if (t < NB) {
            int ex = incl - myh;
            lexcl[t] = ex;
            lcur[t] = ex;
            baseg[t] = atomicAdd(&gcur[t], myh);
        }
        __syncthreads();
#pragma unroll
        for (int s = 0; s < 8; s++) {
            int b = dv[s] >> 7;
            int r = atomicAdd(&lcur[b], 1);
            stage[r] = (unsigned)sv[s] | ((unsigned)dv[s] << 16);
        }
        __syncthreads();
#pragma unroll
        for (int s = 0; s < 8; s++) {
            int idx = s * 512 + t;
            unsigned p = stage[idx];
            int b = (int)(p >> 23);
            binned[baseg[b] + idx - lexcl[b]] = p;
        }
    } else if (blockIdx.x < NB + NN / 4) {
        // ---- layer-1 linear: 4 rows per block ----
        int bid = blockIdx.x - NB;
        int j = t & 127;
        int ty = t >> 7;
        int row = bid * 4 + ty;
        if (t < 64) {
            sx[t >> 4][t & 15] = x[(size_t)(bid * 4 + (t >> 4)) * INF + (t & 15)];
        }
        __syncthreads();
        float al = bl[j], ar = br[j];
#pragma unroll
        for (int k = 0; k < INF; k++) {
            float xv = sx[ty][k];
            al = fmaf(xv, Wl[k * HCC + j], al);
            ar = fmaf(xv, Wr[k * HCC + j], ar);
        }
        size_t s = ((size_t)(j >> 5) * NN + row) * 32 + (j & 31);
        xl[s] = al;
        xr[s] = ar;
    } else {
        // ---- bf16 split-prep of l2 weights into fragment order ----
        int gt = (blockIdx.x - NB - NN / 4) * 512 + t;   // 0..4095
        int ks = gt >> 10;
        int rem = gt & 1023;
        int nt = rem >> 6;
        int lane = rem & 63;
        int n = nt * 16 + (lane & 15);
        int kbase = ks * 32 + (lane >> 4) * 8;
        const float* src = (n < 128) ? (W2l + n) : (W2r + n - 128);
        unsigned short hi8[8], lo8[8];
#pragma unroll
        for (int j = 0; j < 8; j++) {
            float v = src[(size_t)(kbase + j) * HCC];
            unsigned short hb = bf16_rtne(v);
            float hf = __builtin_bit_cast(float, (unsigned)hb << 16);
            hi8[j] = hb;
            lo8[j] = bf16_rtne(v - hf);
        }
        size_t idx = (size_t)gt * 8;
#pragma unroll
        for (int j = 0; j < 8; j++) { Bhi[idx + j] = hi8[j]; Blo[idx + j] = lo8[j]; }
    }
}

// per-bucket: per-(node,phase) histogram + scan -> rowptr & phase-grouped col.
// 512 threads; binned staged in LDS during pass 1 (overflow -> global).
__global__ __launch_bounds__(512) void k_csr(const unsigned* __restrict__ binned,
                                             const int* __restrict__ bbase,
                                             int* __restrict__ rowptr,
                                             int* __restrict__ col) {
    int b = blockIdx.x;
    int base = bbase[b];
    int cnt = bbase[b + 1] - base;
    __shared__ int nh[1024], ncur[1024];   // [node_local(128)][phase(8)]
    __shared__ unsigned sbin[CSRCAP];
    __shared__ int wsum[8];
    int t = threadIdx.x;
    int lane = t & 63, w = t >> 6;
    nh[t] = 0;
    nh[t + 512] = 0;
    __syncthreads();
    for (int e = t; e < cnt; e += 512) {
        unsigned p = binned[base + e];
        if (e < CSRCAP) sbin[e] = p;
        unsigned src = p & 0xFFFFu;
        int key = (int)(((p >> 16) & 127u) << 3) | (int)(src >> 13);
        atomicAdd(&nh[key], 1);
    }
    __syncthreads();
    int c0 = nh[2 * t], c1 = nh[2 * t + 1];
    int tot = c0 + c1;
    int incl = wave_incl_scan(tot, lane);
    if (lane == 63) wsum[w] = incl;
    __syncthreads();
    int woff = 0;
    for (int i = 0; i < w; i++) woff += wsum[i];
    int tex = incl + woff - tot;
    ncur[2 * t] = base + tex;
    ncur[2 * t + 1] = base + tex + c0;
    if ((t & 3) == 0) rowptr[(b << 7) + (t >> 2)] = base + tex;
    __syncthreads();
    for (int e = t; e < cnt; e += 512) {
        unsigned p = (e < CSRCAP) ? sbin[e] : binned[base + e];
        unsigned src = p & 0xFFFFu;
        int key = (int)(((p >> 16) & 127u) << 3) | (int)(src >> 13);
        int r = atomicAdd(&ncur[key], 1);
        col[r] = (int)src;
    }
}

// ---------------- layer-2 linear: split-bf16 MFMA GEMM ----------------
__global__ __launch_bounds__(256) void k_lin2(const float* __restrict__ hin,
                                              const unsigned short* __restrict__ Bhi,
                                              const unsigned short* __restrict__ Blo,
                                              const float* __restrict__ bl,
                                              const float* __restrict__ br,
                                              float* __restrict__ outl,
                                              float* __restrict__ outr) {
    const int tid = threadIdx.x;
    const int wv = tid >> 6;
    const int lane = tid & 63;
    const int m = lane & 15;
    const int quad = lane >> 4;
    const int r0 = blockIdx.x * 64 + wv * 16;
    const float* arow = hin + (size_t)(r0 + m) * HCC + quad * 8;
    const v8s* bh = (const v8s*)Bhi;
    const v8s* bo = (const v8s*)Blo;

    v4f acc[16];
#pragma unroll
    for (int nt = 0; nt < 16; nt++) acc[nt] = (v4f){0.f, 0.f, 0.f, 0.f};

#pragma unroll
    for (int ks = 0; ks < 4; ks++) {
        const float4 av0 = *(const float4*)(arow + ks * 32);
        const float4 av1 = *(const float4*)(arow + ks * 32 + 4);
        const float af[8] = {av0.x, av0.y, av0.z, av0.w, av1.x, av1.y, av1.z, av1.w};
        v8s ahi, alo;
#pragma unroll
        for (int e = 0; e < 8; e++) {
            unsigned short hb = bf16_rtne(af[e]);
            float hf = __builtin_bit_cast(float, (unsigned)hb << 16);
            ahi[e] = (short)hb;
            alo[e] = (short)bf16_rtne(af[e] - hf);
        }
        const int base = ks * 16 * 64 + lane;
#pragma unroll
        for (int nt = 0; nt < 16; nt++) {
            v8s bhv = bh[base + nt * 64];
            v8s blv = bo[base + nt * 64];
            acc[nt] = __builtin_amdgcn_mfma_f32_16x16x32_bf16(ahi, bhv, acc[nt], 0, 0, 0);
            acc[nt] = __builtin_amdgcn_mfma_f32_16x16x32_bf16(ahi, blv, acc[nt], 0, 0, 0);
            acc[nt] = __builtin_amdgcn_mfma_f32_16x16x32_bf16(alo, bhv, acc[nt], 0, 0, 0);
        }
    }
#pragma unroll
    for (int nt = 0; nt < 16; nt++) {
        int n = nt * 16 + m;
        int c = n & 127;
        float bv = (n < 128) ? bl[c] : br[c];
        float* outp = ((n < 128) ? outl : outr) + (size_t)(c >> 5) * NN * 32 + (c & 31);
#pragma unroll
        for (int r = 0; r < 4; r++) {
            int row = r0 + quad * 4 + r;
            outp[(size_t)row * 32] = acc[nt][r] + bv;
        }
    }
}

// ---------------- GATv2 attention, one wave per (node, head-PAIR) ---------
__global__ __launch_bounds__(256) void k_attn(const int* __restrict__ rowptr,
                                              const int* __restrict__ col,
                                              const float* __restrict__ xl,
                                              const float* __restrict__ xr,
                                              const float* __restrict__ att,
                                              const float* __restrict__ bias,
                                              float* __restrict__ hout) {
    const int wave = threadIdx.x >> 6;
    const int lane = threadIdx.x & 63;
    const int sub = lane >> 3;
    const int hl = (lane >> 2) & 1;
    const int hq = lane & 3;
    const int pair = blockIdx.x / NBLK;
    const int n = (blockIdx.x - pair * NBLK) * 4 + wave;
    const int head = 2 * pair + hl;

    const float* xlh = xl + (size_t)head * NN * 32;
    const float* xrp = xr + ((size_t)head * NN + n) * 32 + hq * 8;
    const float4 xrv0 = *(const float4*)(xrp);
    const float4 xrv1 = *(const float4*)(xrp + 4);
    const float4 at0 = *(const float4*)(att + head * 32 + hq * 8);
    const float4 at1 = *(const float4*)(att + head * 32 + hq * 8 + 4);
    const vf2 xr01 = {xrv0.x, xrv0.y}, xr23 = {xrv0.z, xrv0.w};
    const vf2 xr45 = {xrv1.x, xrv1.y}, xr67 = {xrv1.z, xrv1.w};
    const vf2 at01 = {at0.x, at0.y}, at23 = {at0.z, at0.w};
    const vf2 at45 = {at1.x, at1.y}, at67 = {at1.z, at1.w};
    const vf2 Z2 = {0.f, 0.f}, C2 = {0.2f, 0.2f};
    const unsigned choff = (unsigned)hq * 32u;

    const int base = rowptr[n];
    const int deg = rowptr[n + 1] - base;

    float m = -INFINITY, l = 0.f;
    vf2 a01 = Z2, a23 = Z2, a45 = Z2, a67 = Z2;

    for (int i0 = 0; i0 < deg; i0 += 64) {
        int mye = 0;
        if (i0 + lane < deg) mye = col[base + i0 + lane];
        const int cnt = min(64, deg - i0);
        const int events = (cnt + 15) >> 4;
        for (int g = 0; g < events; ++g) {
            float4 v0[2], v1[2];
            float p[2];
#pragma unroll
            for (int k = 0; k < 2; ++k) {
                const int src = __shfl(mye, 16 * g + 8 * k + sub);
                const unsigned voff = ((unsigned)src << 7) + choff;
                v0[k] = *(const float4*)((const char*)xlh + voff);
                v1[k] = *(const float4*)((const char*)xlh + voff + 16);
            }
#pragma unroll
            for (int k = 0; k < 2; ++k) {
                const vf2 v01 = {v0[k].x, v0[k].y}, v23 = {v0[k].z, v0[k].w};
                const vf2 v45 = {v1[k].x, v1[k].y}, v67 = {v1[k].z, v1[k].w};
                vf2 e, kk, p2;
                e = v01 + xr01; kk = FMA2(C2, MIN2(e, Z2), MAX2(e, Z2)); p2 = kk * at01;
                e = v23 + xr23; kk = FMA2(C2, MIN2(e, Z2), MAX2(e, Z2)); p2 = FMA2(kk, at23, p2);
                e = v45 + xr45; kk = FMA2(C2, MIN2(e, Z2), MAX2(e, Z2)); p2 = FMA2(kk, at45, p2);
                e = v67 + xr67; kk = FMA2(C2, MIN2(e, Z2), MAX2(e, Z2)); p2 = FMA2(kk, at67, p2);
                float pp = p2.x + p2.y;
                pp += __shfl_xor(pp, 1);
                pp += __shfl_xor(pp, 2);
                if ((16 * g + 8 * k + sub) >= cnt) pp = -INFINITY;
                p[k] = pp;
            }
            float pm = fmaxf(p[0], p[1]);
            pm = fmaxf(pm, __shfl_xor(pm, 8));
            pm = fmaxf(pm, __shfl_xor(pm, 16));
            pm = fmaxf(pm, __shfl_xor(pm, 32));
            const float mn = fmaxf(m, pm);
            const float sc = __expf(m - mn);
            const float w0 = __expf(p[0] - mn);
            const float w1 = __expf(p[1] - mn);
            l = fmaf(l, sc, w0 + w1);
            const vf2 S = {sc, sc}, W0 = {w0, w0}, W1 = {w1, w1};
            const vf2 u01 = {v0[0].x, v0[0].y}, u23 = {v0[0].z, v0[0].w};
            const vf2 u45 = {v1[0].x, v1[0].y}, u67 = {v1[0].z, v1[0].w};
            const vf2 t01 = {v0[1].x, v0[1].y}, t23 = {v0[1].z, v0[1].w};
            const vf2 t45 = {v1[1].x, v1[1].y}, t67 = {v1[1].z, v1[1].w};
            a01 = FMA2(W1, t01, FMA2(W0, u01, a01 * S));
            a23 = FMA2(W1, t23, FMA2(W0, u23, a23 * S));
            a45 = FMA2(W1, t45, FMA2(W0, u45, a45 * S));
            a67 = FMA2(W1, t67, FMA2(W0, u67, a67 * S));
            m = mn;
        }
    }
    l += __shfl_xor(l, 8);
    l += __shfl_xor(l, 16);
    l += __shfl_xor(l, 32);
    float af[8] = {a01.x, a01.y, a23.x, a23.y, a45.x, a45.y, a67.x, a67.y};
#pragma unroll
    for (int i = 0; i < 8; i++) {
        af[i] += __shfl_xor(af[i], 8);
        af[i] += __shfl_xor(af[i], 16);
        af[i] += __shfl_xor(af[i], 32);
    }
    const float inv = 1.f / (l + 1e-16f);
    if (sub == 0) {
        const float4 b0 = *(const float4*)(bias + head * 32 + hq * 8);
        const float4 b1 = *(const float4*)(bias + head * 32 + hq * 8 + 4);
        float4 o0, o1;
        o0.x = fmaxf(fmaf(af[0], inv, b0.x), 0.f);
        o0.y = fmaxf(fmaf(af[1], inv, b0.y), 0.f);
        o0.z = fmaxf(fmaf(af[2], inv, b0.z), 0.f);
        o0.w = fmaxf(fmaf(af[3], inv, b0.w), 0.f);
        o1.x = fmaxf(fmaf(af[4], inv, b1.x), 0.f);
        o1.y = fmaxf(fmaf(af[5], inv, b1.y), 0.f);
        o1.z = fmaxf(fmaf(af[6], inv, b1.z), 0.f);
        o1.w = fmaxf(fmaf(af[7], inv, b1.w), 0.f);
        float* hp = hout + (size_t)n * HCC + head * 32 + hq * 8;
        *(float4*)(hp) = o0;
        *(float4*)(hp + 4) = o1;
    }
}

// ---------------- pool (sorted batch) + MLP head ----------------
__global__ __launch_bounds__(128) void k_head(const float* __restrict__ h,
                                              const int* __restrict__ batch,
                                              const float* __restrict__ fc1W, const float* __restrict__ fc1b,
                                              const float* __restrict__ bn1g, const float* __restrict__ bn1b,
                                              const float* __restrict__ fc2W, const float* __restrict__ fc2b,
                                              const float* __restrict__ bn2g, const float* __restrict__ bn2b,
                                              const float* __restrict__ fc3W, const float* __restrict__ fc3b,
                                              float* __restrict__ out) {
    int g = blockIdx.x;
    int j = threadIdx.x;
    __shared__ float buf[HCC], buf2[HCC];
    int lo = 0, hi = NN;
    while (lo < hi) { int mid = (lo + hi) >> 1; if (batch[mid] < g) lo = mid + 1; else hi = mid; }
    int s = lo;
    lo = 0; hi = NN;
    while (lo < hi) { int mid = (lo + hi) >> 1; if (batch[mid] < g + 1) lo = mid + 1; else hi = mid; }
    int e = lo;
    float s0 = 0.f, s1 = 0.f, s2 = 0.f, s3 = 0.f;
    int n = s;
    for (; n + 3 < e; n += 4) {
        s0 += h[(size_t)n * HCC + j];
        s1 += h[(size_t)(n + 1) * HCC + j];
        s2 += h[(size_t)(n + 2) * HCC + j];
        s3 += h[(size_t)(n + 3) * HCC + j];
    }
    for (; n < e; n++) s0 += h[(size_t)n * HCC + j];
    float sum = (s0 + s1) + (s2 + s3);
    float cnt = (float)(e - s);
    buf[j] = sum / fmaxf(cnt, 1.0f);
    __syncthreads();
    const float SQ = 1.00000499998749994f;
    float a = fc1b[j];
    for (int k = 0; k < HCC; k++) a = fmaf(buf[k], fc1W[k * HCC + j], a);
    a = fmaf(a, bn1g[j] / SQ, bn1b[j]);
    a = fmaxf(a, 0.f);
    buf2[j] = a;
    __syncthreads();
    a = fc2b[j];
    for (int k = 0; k < HCC; k++) a = fmaf(buf2[k], fc2W[k * HCC + j], a);
    a = fmaf(a, bn2g[j] / SQ, bn2b[j]);
    a = fmaxf(a, 0.f);
    buf[j] = a;
    __syncthreads();
    if (j < 2) {
        float o = fc3b[j];
        for (int k = 0; k < HCC; k++) o = fmaf(buf[k], fc3W[k * 2 + j], o);
        out[g * 2 + j] = o;
    }
}

extern "C" void kernel_launch(void* const* d_in, const int* in_sizes, int n_in,
                              void* d_out, int out_size, void* d_ws, size_t ws_size,
                              hipStream_t stream) {
    const float* x      = (const float*)d_in[0];
    const int*   ei     = (const int*)d_in[1];
    const int*   batch  = (const int*)d_in[2];
    const float* l1_Wl  = (const float*)d_in[3];
    const float* l1_bl  = (const float*)d_in[4];
    const float* l1_Wr  = (const float*)d_in[5];
    const float* l1_br  = (const float*)d_in[6];
    const float* l1_att = (const float*)d_in[7];
    const float* l1_bias= (const float*)d_in[8];
    const float* l2_Wl  = (const float*)d_in[9];
    const float* l2_bl  = (const float*)d_in[10];
    const float* l2_Wr  = (const float*)d_in[11];
    const float* l2_br  = (const float*)d_in[12];
    const float* l2_att = (const float*)d_in[13];
    const float* l2_bias= (const float*)d_in[14];
    const float* fc1_W  = (const float*)d_in[15];
    const float* fc1_b  = (const float*)d_in[16];
    const float* bn1_g  = (const float*)d_in[17];
    const float* bn1_b  = (const float*)d_in[18];
    const float* fc2_W  = (const float*)d_in[19];
    const float* fc2_b  = (const float*)d_in[20];
    const float* bn2_g  = (const float*)d_in[21];
    const float* bn2_b  = (const float*)d_in[22];
    const float* fc3_W  = (const float*)d_in[23];
    const float* fc3_b  = (const float*)d_in[24];
    float* out = (float*)d_out;

    float* xl = (float*)d_ws;
    float* xr = xl + (size_t)NN * HCC;
    float* h  = xr + (size_t)NN * HCC;
    int* rowptr = (int*)(h + (size_t)NN * HCC);
    int* col    = rowptr + (NN + 1);
    int* bcnt   = col + EE;
    int* bbase  = bcnt + NB;
    int* gcur   = bbase + (NB + 1);
    uintptr_t bp = ((uintptr_t)(gcur + NB) + 15) & ~(uintptr_t)15;
    unsigned short* Bhi = (unsigned short*)bp;       // 64 KB, frag-ordered
    unsigned short* Blo = Bhi + 32768;               // 64 KB
    // binned (6.5 MB) aliases h (26 MB): bin/csr complete before attn1 writes h
    unsigned* binned = (unsigned*)h;

    // CSR build (+ fused layer-1 linear + l2-weight bf16 split-prep)
    hipMemsetAsync(bcnt, 0, NB * sizeof(int), stream);
    k_hist<<<EE / TILE, 512, 0, stream>>>(ei, bcnt);
    k_scan2<<<1, 512, 0, stream>>>(bcnt, bbase, gcur, rowptr);
    k_binlin1<<<NB + NN / 4 + 8, 512, 0, stream>>>(ei, gcur, binned,
                                                   x, l1_Wl, l1_bl, l1_Wr, l1_br, xl, xr,
                                                   l2_Wl, l2_Wr, Bhi, Blo);
    k_csr<<<NB, 512, 0, stream>>>(binned, bbase, rowptr, col);

    // layer 1 attention
    k_attn<<<2 * NBLK, 256, 0, stream>>>(rowptr, col, xl, xr, l1_att, l1_bias, h);

    // layer 2
    k_lin2<<<NN / 64, 256, 0, stream>>>(h, Bhi, Blo, l2_bl, l2_br, xl, xr);
    k_attn<<<2 * NBLK, 256, 0, stream>>>(rowptr, col, xl, xr, l2_att, l2_bias, h);

    // pool + MLP head
    k_head<<<GG, 128, 0, stream>>>(h, batch, fc1_W, fc1_b, bn1_g, bn1_b,
                                   fc2_W, fc2_b, bn2_g, bn2_b, fc3_W, fc3_b, out);
}